// Round 5
// baseline (285.573 us; speedup 1.0000x reference)
//
#include <hip/hip_runtime.h>

// Haar DWT, mode=0 (no pad).
// in : (2,16,16,256,256) f32  -> plane pl = b*256 + pcd in [0,512), each plane 256x256
// out: (2,64,16,128,128) f32  -> flat (b*1024 + s*256 + pcd)*16384 + h2*128 + w2
//
// Per 2x2 quad (a=ev/ev, b=od/ev, c=ev/od, d=od/od), all *0.5:
//   LL = a+b+c+d ; HL = -a-b+c+d ; LH = -a+b-c+d ; HH = a-b-c+d
//
// Thread layout: idx = (plane[9b], h2[7b], w8[4b]); w8 indexes groups of 8 output cols.
//   loads : 4x 16B per input row (rows 2h2, 2h2+1) -> 64 B/thread/row contiguous
//   stores: 2x 16B per subband                     -> 16 B/lane, fully coalesced
// Nontemporal both sides: pure streaming, zero reuse. 8 loads in flight/thread for ILP.

typedef float v4f __attribute__((ext_vector_type(4)));

__global__ __launch_bounds__(256) void dwt_haar_fwd(const float* __restrict__ in,
                                                    float* __restrict__ out) {
    const int idx = blockIdx.x * 256 + threadIdx.x;   // 0 .. 1,048,576
    const int w8  = idx & 15;           // group of 8 output cols (16 per 128-wide row)
    const int t   = idx >> 4;
    const int h2  = t & 127;            // output row
    const int pl  = t >> 7;             // input plane 0..511
    const int b   = pl >> 8;            // batch
    const int pcd = pl & 255;           // c*16+d

    const float* rbase = in + pl * 65536 + (h2 << 1) * 256 + (w8 << 4);
    const v4f* p0 = (const v4f*)rbase;           // row 2h2   (4 x v4f)
    const v4f* p1 = (const v4f*)(rbase + 256);   // row 2h2+1 (4 x v4f)
    v4f r0[4], r1[4];
#pragma unroll
    for (int i = 0; i < 4; ++i) r0[i] = __builtin_nontemporal_load(p0 + i);
#pragma unroll
    for (int i = 0; i < 4; ++i) r1[i] = __builtin_nontemporal_load(p1 + i);

    // Each r0[i]/r1[i] pair yields 2 output columns: lanes (a c a' c') over (b d b' d')
    v4f LL[2], HL[2], LH[2], HH[2];
#pragma unroll
    for (int j = 0; j < 2; ++j) {                 // j = output half (cols 4j..4j+3 of the 8)
        const v4f sA = r0[2*j]   + r1[2*j];       // se0 so0 se1 so1
        const v4f sB = r0[2*j+1] + r1[2*j+1];     // se2 so2 se3 so3
        const v4f dA = r0[2*j]   - r1[2*j];       // de0 do0 de1 do1
        const v4f dB = r0[2*j+1] - r1[2*j+1];     // de2 do2 de3 do3
        LL[j] = (v4f){  0.5f*(sA.x+sA.y),  0.5f*(sA.z+sA.w),  0.5f*(sB.x+sB.y),  0.5f*(sB.z+sB.w) };
        HL[j] = (v4f){  0.5f*(sA.y-sA.x),  0.5f*(sA.w-sA.z),  0.5f*(sB.y-sB.x),  0.5f*(sB.w-sB.z) };
        LH[j] = (v4f){ -0.5f*(dA.x+dA.y), -0.5f*(dA.z+dA.w), -0.5f*(dB.x+dB.y), -0.5f*(dB.z+dB.w) };
        HH[j] = (v4f){  0.5f*(dA.x-dA.y),  0.5f*(dA.z-dA.w),  0.5f*(dB.x-dB.y),  0.5f*(dB.w-dB.z) };
    }
    // fix typo-proof: HH[j].w must be 0.5f*(dB.z-dB.w); recompute explicitly
#pragma unroll
    for (int j = 0; j < 2; ++j) {
        const v4f dB = r0[2*j+1] - r1[2*j+1];
        HH[j].w = 0.5f*(dB.z - dB.w);
    }

    float* obase = out + (size_t)(b * 1024 + pcd) * 16384 + (h2 << 7) + (w8 << 3);
#pragma unroll
    for (int j = 0; j < 2; ++j) {
        __builtin_nontemporal_store(LL[j], (v4f*)(obase            + 4*j));  // s=0
        __builtin_nontemporal_store(HL[j], (v4f*)(obase + 4194304  + 4*j));  // s=1
        __builtin_nontemporal_store(LH[j], (v4f*)(obase + 8388608  + 4*j));  // s=2
        __builtin_nontemporal_store(HH[j], (v4f*)(obase + 12582912 + 4*j));  // s=3
    }
}

extern "C" void kernel_launch(void* const* d_in, const int* in_sizes, int n_in,
                              void* d_out, int out_size, void* d_ws, size_t ws_size,
                              hipStream_t stream) {
    const float* x = (const float*)d_in[0];
    float* out = (float*)d_out;
    // total threads = 512 planes * 128 rows * 16 col-octets = 1,048,576
    dwt_haar_fwd<<<4096, 256, 0, stream>>>(x, out);
}

// Round 6
// 225.553 us; speedup vs baseline: 1.2661x; 1.2661x over previous
//
#include <hip/hip_runtime.h>

// Haar DWT, mode=0 (no pad).
// in : (2,16,16,256,256) f32  -> plane pl = b*256 + pcd, each plane 256x256 (row = 1 KiB)
// out: (2,64,16,128,128) f32  -> flat (b*1024 + s*256 + pcd)*16384 + h2*128 + w2
//
// Per 2x2 quad (a=ev/ev, b=od/ev, c=ev/od, d=od/od), all *0.5:
//   LL = a+b+c+d ; HL = -a-b+c+d ; LH = -a+b-c+d ; HH = a-b-c+d
//
// Thread layout: idx = (plane[9b], h4[6b], w4[5b]).
//   Each thread: 2 output rows (h2 = 2*h4, 2*h4+1) x 4 output cols (4*w4..4*w4+3)
//   loads : 4 input rows x 2 v4f (lane stride 32 B; adjacent instrs cover full lines -> L1 merges,
//           FETCH stays ideal — verified R5: no read amplification)
//   stores: v4f per subband per row; lane stride 16 B -> each store instr = 2x contiguous 512-B
//           chunks. R5 lesson: nt stores MUST be per-instruction wave-contiguous or HBM
//           write-amplifies ~2x (WRITE_SIZE 247 MB vs 134 MB ideal).
// Nontemporal both sides: pure streaming, zero reuse.

typedef float v4f __attribute__((ext_vector_type(4)));

__global__ __launch_bounds__(256) void dwt_haar_fwd(const float* __restrict__ in,
                                                    float* __restrict__ out) {
    const int idx = blockIdx.x * 256 + threadIdx.x;   // 0 .. 1,048,576
    const int w4  = idx & 31;           // output col quad (32 per 128-wide row)
    const int t   = idx >> 5;
    const int h4  = t & 63;             // output row PAIR (h2 = 2*h4 + k)
    const int pl  = t >> 6;             // input plane 0..511
    const int b   = pl >> 8;            // batch
    const int pcd = pl & 255;           // c*16+d

    // input rows 4*h4 .. 4*h4+3, cols 8*w4 .. 8*w4+7
    const float* rbase = in + pl * 65536 + (h4 << 2) * 256 + (w4 << 3);
    v4f rA[4], rB[4];                   // rA = cols 8w4..+3 (a c a' c'), rB = cols 8w4+4..+7
#pragma unroll
    for (int r = 0; r < 4; ++r) {
        const v4f* p = (const v4f*)(rbase + 256 * r);
        rA[r] = __builtin_nontemporal_load(p);
        rB[r] = __builtin_nontemporal_load(p + 1);
    }

    // output base: row h2=2*h4 -> (2*h4)*128 = h4<<8 ; col 4*w4
    float* obase = out + (size_t)(b * 1024 + pcd) * 16384 + (h4 << 8) + (w4 << 2);

#pragma unroll
    for (int k = 0; k < 2; ++k) {       // k = which output row of the pair
        const v4f sA = rA[2*k] + rA[2*k+1];   // (a+b, c+d, a'+b', c'+d')
        const v4f sB = rB[2*k] + rB[2*k+1];
        const v4f dA = rA[2*k] - rA[2*k+1];   // (a-b, c-d, a'-b', c'-d')
        const v4f dB = rB[2*k] - rB[2*k+1];

        const v4f LL = {  0.5f*(sA.x+sA.y),  0.5f*(sA.z+sA.w),  0.5f*(sB.x+sB.y),  0.5f*(sB.z+sB.w) };
        const v4f HL = {  0.5f*(sA.y-sA.x),  0.5f*(sA.w-sA.z),  0.5f*(sB.y-sB.x),  0.5f*(sB.w-sB.z) };
        const v4f LH = { -0.5f*(dA.x+dA.y), -0.5f*(dA.z+dA.w), -0.5f*(dB.x+dB.y), -0.5f*(dB.z+dB.w) };
        const v4f HH = {  0.5f*(dA.x-dA.y),  0.5f*(dA.z-dA.w),  0.5f*(dB.x-dB.y),  0.5f*(dB.z-dB.w) };

        float* o = obase + (k << 7);    // +128 floats = next output row
        __builtin_nontemporal_store(LL, (v4f*)(o           ));  // s=0
        __builtin_nontemporal_store(HL, (v4f*)(o + 4194304 ));  // s=1: +256*16384
        __builtin_nontemporal_store(LH, (v4f*)(o + 8388608 ));  // s=2
        __builtin_nontemporal_store(HH, (v4f*)(o + 12582912));  // s=3
    }
}

extern "C" void kernel_launch(void* const* d_in, const int* in_sizes, int n_in,
                              void* d_out, int out_size, void* d_ws, size_t ws_size,
                              hipStream_t stream) {
    const float* x = (const float*)d_in[0];
    float* out = (float*)d_out;
    // total threads = 512 planes * 64 row-pairs * 32 col-quads = 1,048,576
    dwt_haar_fwd<<<4096, 256, 0, stream>>>(x, out);
}